// Round 3
// baseline (237.493 us; speedup 1.0000x reference)
//
#include <hip/hip_runtime.h>

#define LN_EPS 1e-5f

// ---------------------------------------------------------------------------
// Wave (64-lane) sum.
// ---------------------------------------------------------------------------
__device__ __forceinline__ float wave_sum(float v) {
    #pragma unroll
    for (int o = 32; o; o >>= 1) v += __shfl_down(v, o);
    return v;
}

// 1024-thread block sum (16 waves). sh: 16 floats. Result broadcast to all.
__device__ __forceinline__ float block_sum_1024(float v, float* sh) {
    int lane = threadIdx.x & 63, w = threadIdx.x >> 6;
    v = wave_sum(v);
    if (lane == 0) sh[w] = v;
    __syncthreads();
    if (w == 0) {
        float s = (lane < 16) ? sh[lane] : 0.f;
        #pragma unroll
        for (int o = 8; o; o >>= 1) s += __shfl_down(s, o);
        if (lane == 0) sh[0] = s;
    }
    __syncthreads();
    float r = sh[0];
    __syncthreads();
    return r;
}

// ---------------------------------------------------------------------------
// K1: t1 = W_I_H1 @ input (4096x2048), t2 = W_H2_H1 @ h2_prev (4096x4096).
// 4 rows/block (one per wave), x staged in LDS. Per-block (sum,sumsq) of the
// 4 row values -> p1/p2 (deterministic, no atomics, no zero-init needed).
// grid = 1024 + 1024 = 2048 blocks of 256 (8/CU).
// ---------------------------------------------------------------------------
__global__ __launch_bounds__(256) void k1(
        const float* __restrict__ W_I_H1, const float* __restrict__ x_in,
        const float* __restrict__ W_H2_H1, const float* __restrict__ h2_prev,
        float* __restrict__ t1, float* __restrict__ t2,
        float2* __restrict__ p1, float2* __restrict__ p2) {
    extern __shared__ float xs[];
    __shared__ float shy[4];
    const float* W; const float* x; float* y; float2* p; int C; int blk;
    if ((int)blockIdx.x < 1024) {
        W = W_I_H1;  x = x_in;    y = t1; p = p1; C = 2048; blk = blockIdx.x;
    } else {
        W = W_H2_H1; x = h2_prev; y = t2; p = p2; C = 4096; blk = blockIdx.x - 1024;
    }
    int n4 = C >> 2;
    float4* xs4 = (float4*)xs;
    for (int i = threadIdx.x; i < n4; i += 256)
        xs4[i] = ((const float4*)x)[i];
    __syncthreads();

    int wave = threadIdx.x >> 6, lane = threadIdx.x & 63;
    int row = blk * 4 + wave;
    const float4* Wr = (const float4*)(W + (size_t)row * C);
    float acc = 0.f;
    #pragma unroll 4
    for (int i = lane; i < n4; i += 64) {
        float4 w = Wr[i], v = xs4[i];
        acc += w.x * v.x + w.y * v.y + w.z * v.z + w.w * v.w;
    }
    acc = wave_sum(acc);
    if (lane == 0) { y[row] = acc; shy[wave] = acc; }
    __syncthreads();
    if (threadIdx.x == 0) {
        float s = 0.f, q = 0.f;
        #pragma unroll
        for (int i = 0; i < 4; i++) { float v = shy[i]; s += v; q += v * v; }
        p[blk] = make_float2(s, q);
    }
}

// ---------------------------------------------------------------------------
// L1: h1 = tanh(LN(t1)) + tanh(LN(t2)). One block of 1024. Stats from
// partials p1/p2 (1024 entries each, one per thread).
// ---------------------------------------------------------------------------
__global__ __launch_bounds__(1024) void ln2_add(
        const float* __restrict__ t1, const float* __restrict__ t2,
        const float2* __restrict__ p1, const float2* __restrict__ p2,
        const float* __restrict__ g, const float* __restrict__ b,
        float* __restrict__ h1) {
    __shared__ float sh[16];
    int tid = threadIdx.x;
    float2 a = p1[tid], c = p2[tid];
    float s1 = block_sum_1024(a.x, sh), q1 = block_sum_1024(a.y, sh);
    float s2 = block_sum_1024(c.x, sh), q2 = block_sum_1024(c.y, sh);
    const float invN = 1.f / 4096.f;
    float m1 = s1 * invN, r1 = rsqrtf(fmaxf(q1 * invN - m1 * m1, 0.f) + LN_EPS);
    float m2 = s2 * invN, r2 = rsqrtf(fmaxf(q2 * invN - m2 * m2, 0.f) + LN_EPS);

    float4 av = ((const float4*)t1)[tid], cv = ((const float4*)t2)[tid];
    float4 gv = ((const float4*)g)[tid], bv = ((const float4*)b)[tid];
    float4 o;
    o.x = tanhf((av.x - m1) * r1 * gv.x + bv.x) + tanhf((cv.x - m2) * r2 * gv.x + bv.x);
    o.y = tanhf((av.y - m1) * r1 * gv.y + bv.y) + tanhf((cv.y - m2) * r2 * gv.y + bv.y);
    o.z = tanhf((av.z - m1) * r1 * gv.z + bv.z) + tanhf((cv.z - m2) * r2 * gv.z + bv.z);
    o.w = tanhf((av.w - m1) * r1 * gv.w + bv.w) + tanhf((cv.w - m2) * r2 * gv.w + bv.w);
    ((float4*)h1)[tid] = o;
}

// ---------------------------------------------------------------------------
// K2: t3 = W_H1_H2 @ h1 (4096 rows), t4 = W_H1_O @ h1 (1024 rows). C = 4096.
// Light prologue: stage h1 (16 KB) from global into LDS. Partials p3/p4.
// grid = 1024 + 256 = 1280 blocks of 256 (5/CU).
// ---------------------------------------------------------------------------
__global__ __launch_bounds__(256) void k2(
        const float* __restrict__ h1,
        const float* __restrict__ W_H1_H2, const float* __restrict__ W_H1_O,
        float* __restrict__ t3, float* __restrict__ t4,
        float2* __restrict__ p3, float2* __restrict__ p4) {
    extern __shared__ float xs[];
    __shared__ float shy[4];
    float4* xs4 = (float4*)xs;
    for (int i = threadIdx.x; i < 1024; i += 256)
        xs4[i] = ((const float4*)h1)[i];
    __syncthreads();

    const float* W; float* y; float2* p; int blk;
    if ((int)blockIdx.x < 1024) { W = W_H1_H2; y = t3; p = p3; blk = blockIdx.x; }
    else                        { W = W_H1_O;  y = t4; p = p4; blk = blockIdx.x - 1024; }
    int wave = threadIdx.x >> 6, lane = threadIdx.x & 63;
    int row = blk * 4 + wave;
    const float4* Wr = (const float4*)(W + (size_t)row * 4096);
    float acc = 0.f;
    #pragma unroll 4
    for (int i = lane; i < 1024; i += 64) {
        float4 w = Wr[i], v = xs4[i];
        acc += w.x * v.x + w.y * v.y + w.z * v.z + w.w * v.w;
    }
    acc = wave_sum(acc);
    if (lane == 0) { y[row] = acc; shy[wave] = acc; }
    __syncthreads();
    if (threadIdx.x == 0) {
        float s = 0.f, q = 0.f;
        #pragma unroll
        for (int i = 0; i < 4; i++) { float v = shy[i]; s += v; q += v * v; }
        p[blk] = make_float2(s, q);
    }
}

// ---------------------------------------------------------------------------
// L2: h2 = tanh(LN(t3)). One block of 1024, stats from p3.
// ---------------------------------------------------------------------------
__global__ __launch_bounds__(1024) void ln_tanh(
        const float* __restrict__ t3, const float2* __restrict__ p3,
        const float* __restrict__ g, const float* __restrict__ b,
        float* __restrict__ h2) {
    __shared__ float sh[16];
    int tid = threadIdx.x;
    float2 a = p3[tid];
    float s3 = block_sum_1024(a.x, sh), q3 = block_sum_1024(a.y, sh);
    const float invN = 1.f / 4096.f;
    float m3 = s3 * invN, r3 = rsqrtf(fmaxf(q3 * invN - m3 * m3, 0.f) + LN_EPS);

    float4 av = ((const float4*)t3)[tid];
    float4 gv = ((const float4*)g)[tid], bv = ((const float4*)b)[tid];
    float4 o;
    o.x = tanhf((av.x - m3) * r3 * gv.x + bv.x);
    o.y = tanhf((av.y - m3) * r3 * gv.y + bv.y);
    o.z = tanhf((av.z - m3) * r3 * gv.z + bv.z);
    o.w = tanhf((av.w - m3) * r3 * gv.w + bv.w);
    ((float4*)h2)[tid] = o;
}

// ---------------------------------------------------------------------------
// K3: t5 = W_H2_O @ h2 (1024 rows x 4096). 2 rows/block, 2 waves per row
// (each wave does half the row). grid = 512 blocks of 256 (2/CU, 8 waves/CU).
// Partials p5 (512 entries, one per block over its 2 rows).
// ---------------------------------------------------------------------------
__global__ __launch_bounds__(256) void k3(
        const float* __restrict__ h2, const float* __restrict__ W_H2_O,
        float* __restrict__ t5, float2* __restrict__ p5) {
    extern __shared__ float xs[];
    __shared__ float shp[4];
    float4* xs4 = (float4*)xs;
    for (int i = threadIdx.x; i < 1024; i += 256)
        xs4[i] = ((const float4*)h2)[i];
    __syncthreads();

    int wave = threadIdx.x >> 6, lane = threadIdx.x & 63;
    int row  = blockIdx.x * 2 + (wave >> 1);   // waves {0,1}->row0, {2,3}->row1
    int half = wave & 1;
    const float4* Wr = (const float4*)(W_H2_O + (size_t)row * 4096);
    float acc = 0.f;
    int i0 = half * 512 + lane;
    #pragma unroll 8
    for (int k = 0; k < 8; k++) {
        int i = i0 + k * 64;
        float4 w = Wr[i], v = xs4[i];
        acc += w.x * v.x + w.y * v.y + w.z * v.z + w.w * v.w;
    }
    acc = wave_sum(acc);
    if (lane == 0) shp[wave] = acc;
    __syncthreads();
    if (threadIdx.x == 0) {
        float r0 = shp[0] + shp[1], r1 = shp[2] + shp[3];
        t5[blockIdx.x * 2]     = r0;
        t5[blockIdx.x * 2 + 1] = r1;
        p5[blockIdx.x] = make_float2(r0 + r1, r0 * r0 + r1 * r1);
    }
}

// ---------------------------------------------------------------------------
// K4: out = tanh(LN(tanh(LN(t4)) + tanh(LN(t5)))). N = 1024, one block.
// t4 stats from p4 (256 entries), t5 stats from p5 (512 entries).
// ---------------------------------------------------------------------------
__global__ __launch_bounds__(1024) void k4(
        const float* __restrict__ t4, const float* __restrict__ t5,
        const float2* __restrict__ p4, const float2* __restrict__ p5,
        const float* __restrict__ g, const float* __restrict__ b,
        float* __restrict__ out) {
    __shared__ float sh[16];
    int tid = threadIdx.x;
    float a4 = 0.f, c4 = 0.f, a5 = 0.f, c5 = 0.f;
    if (tid < 256) { float2 v = p4[tid]; a4 = v.x; c4 = v.y; }
    if (tid < 512) { float2 w = p5[tid]; a5 = w.x; c5 = w.y; }
    float s4 = block_sum_1024(a4, sh), q4 = block_sum_1024(c4, sh);
    float s5 = block_sum_1024(a5, sh), q5 = block_sum_1024(c5, sh);
    const float invN = 1.f / 1024.f;
    float m4 = s4 * invN, r4 = rsqrtf(fmaxf(q4 * invN - m4 * m4, 0.f) + LN_EPS);
    float m5 = s5 * invN, r5 = rsqrtf(fmaxf(q5 * invN - m5 * m5, 0.f) + LN_EPS);

    float gi = g[tid], bi = b[tid];
    float o = tanhf((t4[tid] - m4) * r4 * gi + bi)
            + tanhf((t5[tid] - m5) * r5 * gi + bi);

    float s = block_sum_1024(o, sh), q = block_sum_1024(o * o, sh);
    float m = s * invN, r = rsqrtf(fmaxf(q * invN - m * m, 0.f) + LN_EPS);
    out[tid] = tanhf((o - m) * r * gi + bi);
}

extern "C" void kernel_launch(void* const* d_in, const int* in_sizes, int n_in,
                              void* d_out, int out_size, void* d_ws, size_t ws_size,
                              hipStream_t stream) {
    const float* input_raw = (const float*)d_in[0];
    const float* h2_prev   = (const float*)d_in[1];
    const float* W_I_H1    = (const float*)d_in[2];
    const float* W_H2_H1   = (const float*)d_in[3];
    const float* W_H1_H2   = (const float*)d_in[4];
    const float* W_H1_O    = (const float*)d_in[5];
    const float* W_H2_O    = (const float*)d_in[6];
    const float* g_H1 = (const float*)d_in[7],  *b_H1 = (const float*)d_in[8];
    const float* g_H2 = (const float*)d_in[9],  *b_H2 = (const float*)d_in[10];
    const float* g_O  = (const float*)d_in[11], *b_O  = (const float*)d_in[12];
    float* out = (float*)d_out;

    float* ws = (float*)d_ws;
    float*  t1 = ws;                        // 4096
    float*  t2 = ws + 4096;                 // 4096
    float*  t3 = ws + 8192;                 // 4096
    float*  t4 = ws + 12288;                // 1024
    float*  t5 = ws + 13312;                // 1024
    float*  h1 = ws + 14336;                // 4096
    float*  h2 = ws + 18432;                // 4096
    float2* p1 = (float2*)(ws + 22528);     // 1024 pairs
    float2* p2 = (float2*)(ws + 24576);     // 1024 pairs
    float2* p3 = (float2*)(ws + 26624);     // 1024 pairs
    float2* p4 = (float2*)(ws + 28672);     // 256 pairs
    float2* p5 = (float2*)(ws + 29184);     // 512 pairs

    const size_t lds = 4096 * sizeof(float);   // 16 KiB x-buffer

    k1<<<2048, 256, lds, stream>>>(W_I_H1, input_raw, W_H2_H1, h2_prev,
                                   t1, t2, p1, p2);
    ln2_add<<<1, 1024, 0, stream>>>(t1, t2, p1, p2, g_H1, b_H1, h1);
    k2<<<1280, 256, lds, stream>>>(h1, W_H1_H2, W_H1_O, t3, t4, p3, p4);
    ln_tanh<<<1, 1024, 0, stream>>>(t3, p3, g_H2, b_H2, h2);
    k3<<<512, 256, lds, stream>>>(h2, W_H2_O, t5, p5);
    k4<<<1, 1024, 0, stream>>>(t4, t5, p4, p5, g_O, b_O, out);
}

// Round 5
// 232.673 us; speedup vs baseline: 1.0207x; 1.0207x over previous
//
#include <hip/hip_runtime.h>

#define LN_EPS 1e-5f

// ---------------------------------------------------------------------------
// Wave (64-lane) sum.
// ---------------------------------------------------------------------------
__device__ __forceinline__ float wave_sum(float v) {
    #pragma unroll
    for (int o = 32; o; o >>= 1) v += __shfl_down(v, o);
    return v;
}

// Block-wide (sum of .x, sum of .y) over 1024 threads (16 waves).
// sh: 16 float2. Result broadcast to all threads. Reusable (trailing sync).
__device__ __forceinline__ float2 block_sum2_1024(float2 v, float2* sh) {
    int lane = threadIdx.x & 63, w = threadIdx.x >> 6;
    #pragma unroll
    for (int o = 32; o; o >>= 1) {
        v.x += __shfl_down(v.x, o);
        v.y += __shfl_down(v.y, o);
    }
    if (lane == 0) sh[w] = v;
    __syncthreads();
    if (w == 0) {
        float2 s = (lane < 16) ? sh[lane] : make_float2(0.f, 0.f);
        #pragma unroll
        for (int o = 8; o; o >>= 1) {
            s.x += __shfl_down(s.x, o);
            s.y += __shfl_down(s.y, o);
        }
        if (lane == 0) sh[0] = s;
    }
    __syncthreads();
    float2 r = sh[0];
    __syncthreads();
    return r;
}

// Stage x into LDS (n4 float4s), all 256 threads, then sync.
__device__ __forceinline__ void stage_x(const float* __restrict__ x, int n4,
                                        float4* __restrict__ xs4) {
    for (int i = threadIdx.x; i < n4; i += 256)
        xs4[i] = ((const float4*)x)[i];
    __syncthreads();
}

// ---------------------------------------------------------------------------
// GEMV worker: 8 rows per block, 2 rows per wave, C = STEPS*256 columns.
// Fully unrolled -> up to STEPS*2 weight loads in flight per wave (MLP), 4
// independent FMA chains. Writes y[r0..r7]; optional per-block (sum,sumsq).
// ---------------------------------------------------------------------------
template<int STEPS>
__device__ __forceinline__ void gemv8(const float* __restrict__ W, int blk,
                                      const float4* __restrict__ xs4,
                                      float* __restrict__ y,
                                      float2* __restrict__ p, bool want_p,
                                      float* __restrict__ shy) {
    const int C = STEPS * 256;
    int wave = threadIdx.x >> 6, lane = threadIdx.x & 63;
    int r0 = blk * 8 + wave * 2;
    const float4* W0 = (const float4*)(W + (size_t)r0 * C);
    const float4* W1 = (const float4*)(W + (size_t)(r0 + 1) * C);
    float a00 = 0.f, a01 = 0.f, a10 = 0.f, a11 = 0.f;
    #pragma unroll
    for (int k = 0; k < STEPS; k++) {
        int i = lane + (k << 6);
        float4 w0 = W0[i], w1 = W1[i], v = xs4[i];
        a00 += w0.x * v.x + w0.y * v.y;
        a01 += w0.z * v.z + w0.w * v.w;
        a10 += w1.x * v.x + w1.y * v.y;
        a11 += w1.z * v.z + w1.w * v.w;
    }
    float v0 = wave_sum(a00 + a01);
    float v1 = wave_sum(a10 + a11);
    if (lane == 0) {
        y[r0] = v0; y[r0 + 1] = v1;
        shy[wave * 2] = v0; shy[wave * 2 + 1] = v1;
    }
    __syncthreads();
    if (want_p && threadIdx.x == 0) {
        float s = 0.f, q = 0.f;
        #pragma unroll
        for (int i = 0; i < 8; i++) { float t = shy[i]; s += t; q += t * t; }
        p[blk] = make_float2(s, q);
    }
}

// ---------------------------------------------------------------------------
// gA: t1 = W_I_H1 @ input (4096x2048), t2 = W_H2_H1 @ h2_prev (4096x4096).
// grid = 512 + 512 = 1024 blocks of 256 (4/CU at 16 waves/CU).
// ---------------------------------------------------------------------------
__global__ __launch_bounds__(256, 4) void gA(
        const float* __restrict__ W_I_H1, const float* __restrict__ x_in,
        const float* __restrict__ W_H2_H1, const float* __restrict__ h2_prev,
        float* __restrict__ t1, float* __restrict__ t2,
        float2* __restrict__ p1, float2* __restrict__ p2) {
    extern __shared__ float xs[];
    __shared__ float shy[8];
    float4* xs4 = (float4*)xs;
    if ((int)blockIdx.x < 512) {
        stage_x(x_in, 512, xs4);
        gemv8<8>(W_I_H1, blockIdx.x, xs4, t1, p1, true, shy);
    } else {
        stage_x(h2_prev, 1024, xs4);
        gemv8<16>(W_H2_H1, blockIdx.x - 512, xs4, t2, p2, true, shy);
    }
}

// ---------------------------------------------------------------------------
// L1: h1 = tanh(LN(t1)) + tanh(LN(t2)). One block of 1024; stats from p1/p2
// (512 entries each).
// ---------------------------------------------------------------------------
__global__ __launch_bounds__(1024) void ln2_add(
        const float* __restrict__ t1, const float* __restrict__ t2,
        const float2* __restrict__ p1, const float2* __restrict__ p2,
        const float* __restrict__ g, const float* __restrict__ b,
        float* __restrict__ h1) {
    __shared__ float2 sh[16];
    int tid = threadIdx.x;
    float2 a = (tid < 512) ? p1[tid] : make_float2(0.f, 0.f);
    float2 c = (tid < 512) ? p2[tid] : make_float2(0.f, 0.f);
    float2 S1 = block_sum2_1024(a, sh);
    float2 S2 = block_sum2_1024(c, sh);
    const float invN = 1.f / 4096.f;
    float m1 = S1.x * invN, r1 = rsqrtf(fmaxf(S1.y * invN - m1 * m1, 0.f) + LN_EPS);
    float m2 = S2.x * invN, r2 = rsqrtf(fmaxf(S2.y * invN - m2 * m2, 0.f) + LN_EPS);

    float4 av = ((const float4*)t1)[tid], cv = ((const float4*)t2)[tid];
    float4 gv = ((const float4*)g)[tid], bv = ((const float4*)b)[tid];
    float4 o;
    o.x = tanhf((av.x - m1) * r1 * gv.x + bv.x) + tanhf((cv.x - m2) * r2 * gv.x + bv.x);
    o.y = tanhf((av.y - m1) * r1 * gv.y + bv.y) + tanhf((cv.y - m2) * r2 * gv.y + bv.y);
    o.z = tanhf((av.z - m1) * r1 * gv.z + bv.z) + tanhf((cv.z - m2) * r2 * gv.z + bv.z);
    o.w = tanhf((av.w - m1) * r1 * gv.w + bv.w) + tanhf((cv.w - m2) * r2 * gv.w + bv.w);
    ((float4*)h1)[tid] = o;
}

// ---------------------------------------------------------------------------
// gB: t3 = W_H1_H2 @ h1 (4096x4096), t4 = W_H1_O @ h1 (1024x4096).
// grid = 512 + 128 = 640 blocks of 256. Partials only for t3.
// ---------------------------------------------------------------------------
__global__ __launch_bounds__(256, 4) void gB(
        const float* __restrict__ h1,
        const float* __restrict__ W_H1_H2, const float* __restrict__ W_H1_O,
        float* __restrict__ t3, float* __restrict__ t4,
        float2* __restrict__ p3) {
    extern __shared__ float xs[];
    __shared__ float shy[8];
    float4* xs4 = (float4*)xs;
    stage_x(h1, 1024, xs4);
    if ((int)blockIdx.x < 512) {
        gemv8<16>(W_H1_H2, blockIdx.x, xs4, t3, p3, true, shy);
    } else {
        gemv8<16>(W_H1_O, blockIdx.x - 512, xs4, t4, (float2*)nullptr, false, shy);
    }
}

// ---------------------------------------------------------------------------
// L2: h2 = tanh(LN(t3)). One block of 1024; stats from p3 (512 entries).
// ---------------------------------------------------------------------------
__global__ __launch_bounds__(1024) void ln_tanh(
        const float* __restrict__ t3, const float2* __restrict__ p3,
        const float* __restrict__ g, const float* __restrict__ b,
        float* __restrict__ h2) {
    __shared__ float2 sh[16];
    int tid = threadIdx.x;
    float2 a = (tid < 512) ? p3[tid] : make_float2(0.f, 0.f);
    float2 S3 = block_sum2_1024(a, sh);
    const float invN = 1.f / 4096.f;
    float m3 = S3.x * invN, r3 = rsqrtf(fmaxf(S3.y * invN - m3 * m3, 0.f) + LN_EPS);

    float4 av = ((const float4*)t3)[tid];
    float4 gv = ((const float4*)g)[tid], bv = ((const float4*)b)[tid];
    float4 o;
    o.x = tanhf((av.x - m3) * r3 * gv.x + bv.x);
    o.y = tanhf((av.y - m3) * r3 * gv.y + bv.y);
    o.z = tanhf((av.z - m3) * r3 * gv.z + bv.z);
    o.w = tanhf((av.w - m3) * r3 * gv.w + bv.w);
    ((float4*)h2)[tid] = o;
}

// ---------------------------------------------------------------------------
// gC: t5 = W_H2_O @ h2 (1024x4096). 256 blocks, 1 row per wave, fully
// unrolled 16 loads in flight -> entire 16 MB in flight across the grid.
// ---------------------------------------------------------------------------
__global__ __launch_bounds__(256, 4) void gC(
        const float* __restrict__ h2, const float* __restrict__ W_H2_O,
        float* __restrict__ t5) {
    extern __shared__ float xs[];
    float4* xs4 = (float4*)xs;
    stage_x(h2, 1024, xs4);
    int wave = threadIdx.x >> 6, lane = threadIdx.x & 63;
    int row = blockIdx.x * 4 + wave;
    const float4* Wr = (const float4*)(W_H2_O + (size_t)row * 4096);
    float a0 = 0.f, a1 = 0.f, a2 = 0.f, a3 = 0.f;
    #pragma unroll
    for (int k = 0; k < 16; k++) {
        int i = lane + (k << 6);
        float4 w = Wr[i], v = xs4[i];
        a0 += w.x * v.x; a1 += w.y * v.y; a2 += w.z * v.z; a3 += w.w * v.w;
    }
    float r = wave_sum((a0 + a1) + (a2 + a3));
    if (lane == 0) t5[row] = r;
}

// ---------------------------------------------------------------------------
// K4: out = tanh(LN(tanh(LN(t4)) + tanh(LN(t5)))). N = 1024, one block.
// All stats computed directly via paired block reductions.
// ---------------------------------------------------------------------------
__global__ __launch_bounds__(1024) void k4(
        const float* __restrict__ t4, const float* __restrict__ t5,
        const float* __restrict__ g, const float* __restrict__ b,
        float* __restrict__ out) {
    __shared__ float2 sh[16];
    int tid = threadIdx.x;
    const float invN = 1.f / 1024.f;
    float x4 = t4[tid], x5 = t5[tid];
    float2 S4 = block_sum2_1024(make_float2(x4, x4 * x4), sh);
    float2 S5 = block_sum2_1024(make_float2(x5, x5 * x5), sh);
    float m4 = S4.x * invN, r4 = rsqrtf(fmaxf(S4.y * invN - m4 * m4, 0.f) + LN_EPS);
    float m5 = S5.x * invN, r5 = rsqrtf(fmaxf(S5.y * invN - m5 * m5, 0.f) + LN_EPS);

    float gi = g[tid], bi = b[tid];
    float o = tanhf((x4 - m4) * r4 * gi + bi)
            + tanhf((x5 - m5) * r5 * gi + bi);

    float2 SO = block_sum2_1024(make_float2(o, o * o), sh);
    float m = SO.x * invN, r = rsqrtf(fmaxf(SO.y * invN - m * m, 0.f) + LN_EPS);
    out[tid] = tanhf((o - m) * r * gi + bi);
}

extern "C" void kernel_launch(void* const* d_in, const int* in_sizes, int n_in,
                              void* d_out, int out_size, void* d_ws, size_t ws_size,
                              hipStream_t stream) {
    const float* input_raw = (const float*)d_in[0];
    const float* h2_prev   = (const float*)d_in[1];
    const float* W_I_H1    = (const float*)d_in[2];
    const float* W_H2_H1   = (const float*)d_in[3];
    const float* W_H1_H2   = (const float*)d_in[4];
    const float* W_H1_O    = (const float*)d_in[5];
    const float* W_H2_O    = (const float*)d_in[6];
    const float* g_H1 = (const float*)d_in[7],  *b_H1 = (const float*)d_in[8];
    const float* g_H2 = (const float*)d_in[9],  *b_H2 = (const float*)d_in[10];
    const float* g_O  = (const float*)d_in[11], *b_O  = (const float*)d_in[12];
    float* out = (float*)d_out;

    float* ws = (float*)d_ws;
    float*  t1 = ws;                        // 4096
    float*  t2 = ws + 4096;                 // 4096
    float*  t3 = ws + 8192;                 // 4096
    float*  t4 = ws + 12288;                // 1024
    float*  t5 = ws + 13312;                // 1024
    float*  h1 = ws + 14336;                // 4096
    float*  h2 = ws + 18432;                // 4096
    float2* p1 = (float2*)(ws + 22528);     // 512 pairs
    float2* p2 = (float2*)(ws + 23552);     // 512 pairs
    float2* p3 = (float2*)(ws + 24576);     // 512 pairs

    const size_t lds = 4096 * sizeof(float);   // 16 KiB x-buffer

    gA<<<1024, 256, lds, stream>>>(W_I_H1, input_raw, W_H2_H1, h2_prev,
                                   t1, t2, p1, p2);
    ln2_add<<<1, 1024, 0, stream>>>(t1, t2, p1, p2, g_H1, b_H1, h1);
    gB<<<640, 256, lds, stream>>>(h1, W_H1_H2, W_H1_O, t3, t4, p3);
    ln_tanh<<<1, 1024, 0, stream>>>(t3, p3, g_H2, b_H2, h2);
    gC<<<256, 256, lds, stream>>>(h2, W_H2_O, t5);
    k4<<<1, 1024, 0, stream>>>(t4, t5, g_O, b_O, out);
}